// Round 2
// baseline (328.137 us; speedup 1.0000x reference)
//
#include <hip/hip_runtime.h>
#include <stdint.h>

// Problem constants
#define BB 4
#define CC 256
#define HH 96
#define WW 96
#define HP 98      // halo-padded spatial dim
#define CP 264     // padded k-stride per x (ush); 16B-aligned frags, clean banks
#define XT 16      // x positions per block
#define YT 3       // y rows per block
#define XE 18      // staged x entries (16 + 2 halo)
#define RE 5       // staged rows (3 + 2 halo)
#define ROW (XE * CP)   // 4752 ush per staged row

typedef __bf16 bf16x8 __attribute__((ext_vector_type(8)));
typedef float f32x4 __attribute__((ext_vector_type(4)));

__device__ __forceinline__ uint16_t f2bf(float f) {
    uint32_t u = __float_as_uint(f);
    u += 0x7FFFu + ((u >> 16) & 1u);   // round-to-nearest-even
    return (uint16_t)(u >> 16);
}

// ---------------------------------------------------------------------------
// Pre-kernel 1: cen (NCHW fp32) -> cenT [b][hy 98][hx 98][264] bf16, halo=0.
// Block = (y, b, c-half): 128 channels each -> 25.6 KB LDS, 6 blocks/CU.
// ---------------------------------------------------------------------------
__global__ void transpose_cen(const float* __restrict__ cen, uint16_t* __restrict__ cenT) {
    const int y = blockIdx.x, b = blockIdx.y, ch = blockIdx.z, tid = threadIdx.x;
    __shared__ uint16_t ldsX[128 * 100];

    #pragma unroll
    for (int i = 0; i < 12; ++i) {
        int f = i * 256 + tid;            // 0..3071: 128 c x 24 xq
        int c = f / 24, xq = f % 24;
        float4 v = *(const float4*)(cen + ((((size_t)b * CC + ch * 128 + c) * HH + y) * WW + xq * 4));
        uint2 pk;
        pk.x = (uint32_t)f2bf(v.x) | ((uint32_t)f2bf(v.y) << 16);
        pk.y = (uint32_t)f2bf(v.z) | ((uint32_t)f2bf(v.w) << 16);
        *(uint2*)(&ldsX[c * 100 + xq * 4]) = pk;
    }
    __syncthreads();
    #pragma unroll
    for (int i = 0; i < 6; ++i) {
        int t = i * 256 + tid;            // 0..1535: 96 x * 16 cq
        int x = t % 96, cq = t / 96;
        uint32_t w0, w1, w2, w3;
        w0 = (uint32_t)ldsX[(cq * 8 + 0) * 100 + x] | ((uint32_t)ldsX[(cq * 8 + 1) * 100 + x] << 16);
        w1 = (uint32_t)ldsX[(cq * 8 + 2) * 100 + x] | ((uint32_t)ldsX[(cq * 8 + 3) * 100 + x] << 16);
        w2 = (uint32_t)ldsX[(cq * 8 + 4) * 100 + x] | ((uint32_t)ldsX[(cq * 8 + 5) * 100 + x] << 16);
        w3 = (uint32_t)ldsX[(cq * 8 + 6) * 100 + x] | ((uint32_t)ldsX[(cq * 8 + 7) * 100 + x] << 16);
        size_t o = (((size_t)b * HP + (y + 1)) * HP + (x + 1)) * CP + ch * 128 + cq * 8;
        *(uint4*)(cenT + o) = make_uint4(w0, w1, w2, w3);
    }
}

// ---------------------------------------------------------------------------
// Pre-kernel 2: W3 [9][256 n][256 k] fp32 -> W3bf [9][8 ks][256 n][32 k] bf16.
// A wave's W-fragment (A-operand: A[m=ch][k]) = 1KiB contiguous chunk.
// ---------------------------------------------------------------------------
__global__ void cvt_w3(const float* __restrict__ W3, uint16_t* __restrict__ W3bf) {
    int e = (blockIdx.x * 256 + threadIdx.x) * 4;   // 0..589823
    int g = e >> 16, rem = e & 65535, n = rem >> 8, k = rem & 255;
    float4 v = *(const float4*)(W3 + e);
    uint2 pk;
    pk.x = (uint32_t)f2bf(v.x) | ((uint32_t)f2bf(v.y) << 16);
    pk.y = (uint32_t)f2bf(v.z) | ((uint32_t)f2bf(v.w) << 16);
    size_t o = (((size_t)(g * 8 + (k >> 5)) * 256 + n) * 32) + (k & 31);
    *(uint2*)(W3bf + o) = pk;
}

// ---------------------------------------------------------------------------
// Main kernel: grid (6 xt, 32 yt, 4 b) = 768 blocks = exactly 3/CU, 8 waves.
// Block tile: M = 48 positions (3 rows x 16 x), N = 256 ch, K = 256.
// Wave w owns ch-tiles {2w, 2w+1} for all 3 row-tiles.
// MFMA orientation: D[ch][pos] = W3[g] . cen-shift  (A-operand = W-frag from
// global/L2, B-operand = position-frag from LDS). D col = position=m15 =>
// per-position norm reduces over q-lanes only: 2 shfl hops, 3 LDS atomics.
// ---------------------------------------------------------------------------
__global__ __launch_bounds__(512, 6)
void ecm_main(const float* __restrict__ cen, const uint16_t* __restrict__ cenT,
              const uint16_t* __restrict__ W3bf, float* __restrict__ out) {
    const int tid = threadIdx.x;
    const int wv = tid >> 6, lane = tid & 63, m15 = lane & 15, q = lane >> 4;
    const int x0 = blockIdx.x * XT, y0 = blockIdx.y * YT, b = blockIdx.z;

    __shared__ __align__(16) uint16_t ldsA[RE * ROW];   // 47,520 B
    __shared__ float ldsP[2][48];                        // norm partial slots

    // Stage A: cenT halo-rows y0..y0+4 (positions y0-1..y0+3), x entries x0..x0+17.
    for (int r = 0; r < RE; ++r) {
        const uint4* gs = (const uint4*)(cenT + (((size_t)b * HP + (y0 + r)) * HP + x0) * CP);
        uint4* ls = (uint4*)(ldsA + r * ROW);
        for (int c2 = tid; c2 < ROW / 8; c2 += 512) ls[c2] = gs[c2];
    }
    if (tid < 96) ((float*)ldsP)[tid] = 0.f;
    __syncthreads();

    const int DY[9] = {-1, -1, -1, 0, 1, 1, 1, 0, 0};
    const int DX[9] = {-1, 0, 1, 1, 1, 0, -1, -1, 0};

    const int lane_a = m15 * CP + q * 8;                        // ush
    const int nb0 = ((wv * 2) * 16 + m15) * 32 + q * 8;         // ush, in [256][32] ks-block
    const int nb1 = nb0 + 16 * 32;

    f32x4 fin[3][2] = {};

    for (int g = 0; g < 9; ++g) {
        const int aoff = lane_a + (DY[g] + 1) * ROW + (DX[g] + 1) * CP;
        const float sgn = (g < 8) ? -1.f : 1.f;
        const uint16_t* w3g = W3bf + (size_t)g * 65536;

        f32x4 acc[3][2] = {};
        #pragma unroll
        for (int ks = 0; ks < 8; ++ks) {
            bf16x8 w0 = *(const bf16x8*)(w3g + ks * 8192 + nb0);
            bf16x8 w1 = *(const bf16x8*)(w3g + ks * 8192 + nb1);
            bf16x8 c0 = *(const bf16x8*)(ldsA + aoff + 0 * ROW + ks * 32);
            bf16x8 c1 = *(const bf16x8*)(ldsA + aoff + 1 * ROW + ks * 32);
            bf16x8 c2 = *(const bf16x8*)(ldsA + aoff + 2 * ROW + ks * 32);
            acc[0][0] = __builtin_amdgcn_mfma_f32_16x16x32_bf16(w0, c0, acc[0][0], 0, 0, 0);
            acc[1][0] = __builtin_amdgcn_mfma_f32_16x16x32_bf16(w0, c1, acc[1][0], 0, 0, 0);
            acc[2][0] = __builtin_amdgcn_mfma_f32_16x16x32_bf16(w0, c2, acc[2][0], 0, 0, 0);
            acc[0][1] = __builtin_amdgcn_mfma_f32_16x16x32_bf16(w1, c0, acc[0][1], 0, 0, 0);
            acc[1][1] = __builtin_amdgcn_mfma_f32_16x16x32_bf16(w1, c1, acc[1][1], 0, 0, 0);
            acc[2][1] = __builtin_amdgcn_mfma_f32_16x16x32_bf16(w1, c2, acc[2][1], 0, 0, 0);
        }

        // Per-position ||Y||^2: lane (q,m15) holds ch rows q*4+r (both j), col=pos=m15.
        float ss[3];
        #pragma unroll
        for (int mt = 0; mt < 3; ++mt) {
            float s = 0.f;
            #pragma unroll
            for (int j = 0; j < 2; ++j)
                #pragma unroll
                for (int r = 0; r < 4; ++r)
                    s += acc[mt][j][r] * acc[mt][j][r];
            s += __shfl_xor(s, 16, 64);
            s += __shfl_xor(s, 32, 64);
            ss[mt] = s;
        }
        if (q == 0) {
            #pragma unroll
            for (int mt = 0; mt < 3; ++mt)
                atomicAdd(&ldsP[g & 1][mt * 16 + m15], ss[mt]);
        }
        __syncthreads();

        #pragma unroll
        for (int mt = 0; mt < 3; ++mt) {
            float nrm = ldsP[g & 1][mt * 16 + m15];
            float sc = sgn / fmaxf(sqrtf(nrm), 1e-12f);
            #pragma unroll
            for (int j = 0; j < 2; ++j)
                #pragma unroll
                for (int r = 0; r < 4; ++r)
                    fin[mt][j][r] += acc[mt][j][r] * sc;
        }
        if (tid < 48) ldsP[(g + 1) & 1][tid] = 0.f;
        __syncthreads();
    }

    // Epilogue: out = fin + cen. Lane m15 -> x (64B contiguous per ch-row).
    #pragma unroll
    for (int mt = 0; mt < 3; ++mt)
        #pragma unroll
        for (int j = 0; j < 2; ++j)
            #pragma unroll
            for (int r = 0; r < 4; ++r) {
                int chn = (wv * 2 + j) * 16 + q * 4 + r;
                size_t o = (((size_t)b * CC + chn) * HH + (y0 + mt)) * WW + (x0 + m15);
                out[o] = fin[mt][j][r] + cen[o];
            }
}

extern "C" void kernel_launch(void* const* d_in, const int* in_sizes, int n_in,
                              void* d_out, int out_size, void* d_ws, size_t ws_size,
                              hipStream_t stream) {
    const float* cen = (const float*)d_in[0];
    // d_in[1] = W1, d_in[2] = W2: dead code (softmax over size-1 axis == 1.0)
    const float* W3 = (const float*)d_in[3];
    float* out = (float*)d_out;

    uint16_t* cenT = (uint16_t*)d_ws;                         // [4][98][98][264] bf16
    const size_t cenT_elems = (size_t)BB * HP * HP * CP;
    uint16_t* W3bf = cenT + cenT_elems;                       // [9][8][256][32] bf16

    hipMemsetAsync(d_ws, 0, cenT_elems * sizeof(uint16_t), stream);   // zero halos
    transpose_cen<<<dim3(HH, BB, 2), 256, 0, stream>>>(cen, cenT);
    cvt_w3<<<576, 256, 0, stream>>>(W3, W3bf);
    ecm_main<<<dim3(6, 32, 4), 512, 0, stream>>>(cen, cenT, W3bf, out);
}

// Round 3
// 183.004 us; speedup vs baseline: 1.7931x; 1.7931x over previous
//
#include <hip/hip_runtime.h>
#include <stdint.h>

// Problem constants
#define BB 4
#define CC 256
#define HH 96
#define WW 96
#define HP 98      // halo-padded spatial dim
#define CP 264     // k-stride per x in ush (528 B; 132 words, %32=4 -> measured conflict-free b128 frags)
#define XT 32      // x positions per block
#define YT 2       // y rows per block
#define XE 34      // staged x entries (32 + 2 halo)

typedef __bf16 bf16x8 __attribute__((ext_vector_type(8)));
typedef float f32x4 __attribute__((ext_vector_type(4)));
typedef float f32x16 __attribute__((ext_vector_type(16)));

__device__ __forceinline__ uint16_t f2bf(float f) {
    uint32_t u = __float_as_uint(f);
    u += 0x7FFFu + ((u >> 16) & 1u);   // round-to-nearest-even
    return (uint16_t)(u >> 16);
}

// ---------------------------------------------------------------------------
// Pre-kernel 1: cen (NCHW fp32) -> cenT [b][hy 98][hx 98][264] bf16 (halo=0 via
// prior memset). Block = (y, b, 64-ch chunk): 12.8 KB LDS, high occupancy.
// ---------------------------------------------------------------------------
__global__ void transpose_cen(const float* __restrict__ cen, uint16_t* __restrict__ cenT) {
    const int y = blockIdx.x, b = blockIdx.y, ck = blockIdx.z, tid = threadIdx.x;
    __shared__ uint16_t ldsX[64 * 100];

    #pragma unroll
    for (int i = 0; i < 6; ++i) {
        int f = i * 256 + tid;            // 0..1535: 64 c x 24 xq
        int c = f / 24, xq = f % 24;
        float4 v = *(const float4*)(cen + ((((size_t)b * CC + ck * 64 + c) * HH + y) * WW + xq * 4));
        uint2 pk;
        pk.x = (uint32_t)f2bf(v.x) | ((uint32_t)f2bf(v.y) << 16);
        pk.y = (uint32_t)f2bf(v.z) | ((uint32_t)f2bf(v.w) << 16);
        *(uint2*)(&ldsX[c * 100 + xq * 4]) = pk;
    }
    __syncthreads();
    #pragma unroll
    for (int i = 0; i < 3; ++i) {
        int t = i * 256 + tid;            // 0..767: 96 x * 8 cq
        int x = t % 96, cq = t / 96;
        uint32_t w0, w1, w2, w3;
        w0 = (uint32_t)ldsX[(cq * 8 + 0) * 100 + x] | ((uint32_t)ldsX[(cq * 8 + 1) * 100 + x] << 16);
        w1 = (uint32_t)ldsX[(cq * 8 + 2) * 100 + x] | ((uint32_t)ldsX[(cq * 8 + 3) * 100 + x] << 16);
        w2 = (uint32_t)ldsX[(cq * 8 + 4) * 100 + x] | ((uint32_t)ldsX[(cq * 8 + 5) * 100 + x] << 16);
        w3 = (uint32_t)ldsX[(cq * 8 + 6) * 100 + x] | ((uint32_t)ldsX[(cq * 8 + 7) * 100 + x] << 16);
        size_t o = (((size_t)b * HP + (y + 1)) * HP + (x + 1)) * CP + ck * 64 + cq * 8;
        *(uint4*)(cenT + o) = make_uint4(w0, w1, w2, w3);
    }
}

// ---------------------------------------------------------------------------
// Pre-kernel 2: W3 [9][256 n][256 k] fp32 -> W3bf [g][t 8][ks 16][m 32][kh 2][8]
// A-frag (32x32x16: lane m=lane&31 holds k = (lane>>5)*8 + i) for (g,t,ks) is
// then a 1 KiB contiguous chunk: one fully-coalesced b128/lane global load.
// ---------------------------------------------------------------------------
__global__ void cvt_w3(const float* __restrict__ W3, uint16_t* __restrict__ W3bf) {
    int e = (blockIdx.x * 256 + threadIdx.x) * 4;   // 0..589823
    int g = e >> 16, n = (e >> 8) & 255, k = e & 255;
    float4 v = *(const float4*)(W3 + e);
    uint2 pk;
    pk.x = (uint32_t)f2bf(v.x) | ((uint32_t)f2bf(v.y) << 16);
    pk.y = (uint32_t)f2bf(v.z) | ((uint32_t)f2bf(v.w) << 16);
    size_t o = (size_t)(((g * 8 + (n >> 5)) * 16 + (k >> 4)) * 512)
             + (n & 31) * 16 + ((k >> 3) & 1) * 8 + (k & 7);
    *(uint2*)(W3bf + o) = pk;
}

// ---------------------------------------------------------------------------
// Main kernel: grid (3 xt, 48 yt, 4 b) = 576 blocks, 512 thr (8 waves).
// Block tile: 64 positions (2 rows x 32 x) x 256 ch; wave w = ch-tile w (32 ch).
// mfma_f32_32x32x16_bf16: D[ch][pos]; A = W3 frag (global, 4-ks register
// residency, reused over both row-tiles); B = shifted-cen frag (LDS).
// Per-g norm: 16 in-lane FMA + shfl_xor(32) + ldsP[pos][wave]; every lane
// re-reads the 8 wave-partials (2x b128) -> no second reduction kernel.
// ---------------------------------------------------------------------------
__global__ __launch_bounds__(512, 4)
void ecm_main(const float* __restrict__ cen, const uint16_t* __restrict__ cenT,
              const uint16_t* __restrict__ W3bf, float* __restrict__ out) {
    const int tid = threadIdx.x;
    const int wv = tid >> 6, lane = tid & 63, col = lane & 31, kh = lane >> 5;
    const int x0 = blockIdx.x * XT, y0 = blockIdx.y * YT, b = blockIdx.z;

    __shared__ __align__(16) uint16_t ldsA[YT * XE * CP];   // 35,904 B
    __shared__ __align__(16) float ldsP[64][8];             // per-pos, per-wave ||.||^2 partials

    // g processed in dy-groups; dgOrd[idx] = reference g index, dx = idx%3 - 1.
    const int dgOrd[9] = {0, 1, 2, 7, 8, 3, 6, 5, 4};

    const uint16_t* wlane = W3bf + (size_t)wv * 16 * 512 + col * 16 + kh * 8;
    const int bf_base = kh * 8;   // + xe*CP + ks*16

    f32x16 fin0 = {}, fin1 = {};

    for (int idx = 0; idx < 9; ++idx) {
        const int g = dgOrd[idx], dg = idx / 3, dx = idx % 3 - 1;

        if (idx % 3 == 0) {
            // Stage position-rows (y0+dg-1, y0+dg): cenT rows hy = y0+dg, y0+dg+1.
            for (int r = 0; r < YT; ++r) {
                const uint4* gs = (const uint4*)(cenT + (((size_t)b * HP + (y0 + dg + r)) * HP + x0) * CP);
                uint4* ls = (uint4*)(ldsA + r * XE * CP);
                for (int c = tid; c < XE * CP / 8; c += 512) ls[c] = gs[c];
            }
            __syncthreads();
        }

        const uint16_t* wg = wlane + (size_t)g * 8 * 16 * 512;
        const int a0 = (0 * XE + col + dx + 1) * CP + bf_base;
        const int a1 = (1 * XE + col + dx + 1) * CP + bf_base;

        f32x16 acc0 = {}, acc1 = {};
        #pragma unroll
        for (int kq = 0; kq < 4; ++kq) {
            bf16x8 w0 = *(const bf16x8*)(wg + (kq * 4 + 0) * 512);
            bf16x8 w1 = *(const bf16x8*)(wg + (kq * 4 + 1) * 512);
            bf16x8 w2 = *(const bf16x8*)(wg + (kq * 4 + 2) * 512);
            bf16x8 w3 = *(const bf16x8*)(wg + (kq * 4 + 3) * 512);
            #pragma unroll
            for (int i = 0; i < 4; ++i) {
                const int ks = kq * 4 + i;
                bf16x8 wf = (i == 0) ? w0 : (i == 1) ? w1 : (i == 2) ? w2 : w3;
                bf16x8 b0 = *(const bf16x8*)(ldsA + a0 + ks * 16);
                bf16x8 b1 = *(const bf16x8*)(ldsA + a1 + ks * 16);
                acc0 = __builtin_amdgcn_mfma_f32_32x32x16_bf16(wf, b0, acc0, 0, 0, 0);
                acc1 = __builtin_amdgcn_mfma_f32_32x32x16_bf16(wf, b1, acc1, 0, 0, 0);
            }
        }

        // Per-position ||Y||^2 partial over this wave's 32 ch.
        float s0 = 0.f, s1 = 0.f;
        #pragma unroll
        for (int r = 0; r < 16; ++r) { s0 += acc0[r] * acc0[r]; s1 += acc1[r] * acc1[r]; }
        s0 += __shfl_xor(s0, 32, 64);
        s1 += __shfl_xor(s1, 32, 64);
        if (kh == 0) { ldsP[col][wv] = s0; ldsP[32 + col][wv] = s1; }
        __syncthreads();

        // Every lane combines the 8 wave-partials for its position.
        f32x4 pa = *(const f32x4*)&ldsP[col][0];
        f32x4 pb = *(const f32x4*)&ldsP[col][4];
        f32x4 qa = *(const f32x4*)&ldsP[32 + col][0];
        f32x4 qb = *(const f32x4*)&ldsP[32 + col][4];
        float n0 = pa[0] + pa[1] + pa[2] + pa[3] + pb[0] + pb[1] + pb[2] + pb[3];
        float n1 = qa[0] + qa[1] + qa[2] + qa[3] + qb[0] + qb[1] + qb[2] + qb[3];
        const float sgn = (g == 8) ? 1.f : -1.f;
        float sc0 = sgn / fmaxf(sqrtf(n0), 1e-12f);
        float sc1 = sgn / fmaxf(sqrtf(n1), 1e-12f);
        #pragma unroll
        for (int r = 0; r < 16; ++r) { fin0[r] += acc0[r] * sc0; fin1[r] += acc1[r] * sc1; }
        __syncthreads();   // ldsP WAR + ldsA WAR (before next g / next staging)
    }

    // Epilogue: out = fin + cen. D row->ch: (reg&3) + 8*(reg>>2) + 4*kh (+32*wv).
    #pragma unroll
    for (int r = 0; r < 16; ++r) {
        int ch = wv * 32 + (r & 3) + 8 * (r >> 2) + 4 * kh;
        size_t o0 = (((size_t)b * CC + ch) * HH + y0) * WW + (x0 + col);
        size_t o1 = o0 + WW;
        out[o0] = fin0[r] + cen[o0];
        out[o1] = fin1[r] + cen[o1];
    }
}

extern "C" void kernel_launch(void* const* d_in, const int* in_sizes, int n_in,
                              void* d_out, int out_size, void* d_ws, size_t ws_size,
                              hipStream_t stream) {
    const float* cen = (const float*)d_in[0];
    // d_in[1] = W1, d_in[2] = W2: dead code (softmax over size-1 axis == 1.0)
    const float* W3 = (const float*)d_in[3];
    float* out = (float*)d_out;

    uint16_t* cenT = (uint16_t*)d_ws;                         // [4][98][98][264] bf16
    const size_t cenT_elems = (size_t)BB * HP * HP * CP;
    uint16_t* W3bf = cenT + cenT_elems;                       // [9][8][16][512] bf16

    hipMemsetAsync(d_ws, 0, cenT_elems * sizeof(uint16_t), stream);   // zero halos
    transpose_cen<<<dim3(HH, BB, 4), 256, 0, stream>>>(cen, cenT);
    cvt_w3<<<576, 256, 0, stream>>>(W3, W3bf);
    ecm_main<<<dim3(3, 48, 4), 512, 0, stream>>>(cen, cenT, W3bf, out);
}

// Round 4
// 180.568 us; speedup vs baseline: 1.8172x; 1.0135x over previous
//
#include <hip/hip_runtime.h>
#include <stdint.h>

// Problem constants
#define BB 4
#define CC 256
#define HH 96
#define WW 96
#define HP 98      // halo-padded spatial dim
#define CP 264     // k-stride per x in ush (528 B; measured near-conflict-free b128 frags)
#define XT 32      // x positions per block
#define YT 2       // y rows per block
#define XE 34      // staged x entries (32 + 2 halo)

typedef __bf16 bf16x8 __attribute__((ext_vector_type(8)));
typedef float f32x4 __attribute__((ext_vector_type(4)));
typedef float f32x16 __attribute__((ext_vector_type(16)));

__device__ __forceinline__ uint16_t f2bf(float f) {
    uint32_t u = __float_as_uint(f);
    u += 0x7FFFu + ((u >> 16) & 1u);   // round-to-nearest-even
    return (uint16_t)(u >> 16);
}

// ---------------------------------------------------------------------------
// Pre-kernel 1: cen (NCHW fp32) -> cenT [b][hy 98][hx 98][264] bf16 (halo=0 via
// prior memset). Block = (y, b, c-half): 25.6 KB LDS.
// ---------------------------------------------------------------------------
__global__ void transpose_cen(const float* __restrict__ cen, uint16_t* __restrict__ cenT) {
    const int y = blockIdx.x, b = blockIdx.y, ch = blockIdx.z, tid = threadIdx.x;
    __shared__ uint16_t ldsX[128 * 100];

    #pragma unroll
    for (int i = 0; i < 12; ++i) {
        int f = i * 256 + tid;            // 0..3071: 128 c x 24 xq
        int c = f / 24, xq = f % 24;
        float4 v = *(const float4*)(cen + ((((size_t)b * CC + ch * 128 + c) * HH + y) * WW + xq * 4));
        uint2 pk;
        pk.x = (uint32_t)f2bf(v.x) | ((uint32_t)f2bf(v.y) << 16);
        pk.y = (uint32_t)f2bf(v.z) | ((uint32_t)f2bf(v.w) << 16);
        *(uint2*)(&ldsX[c * 100 + xq * 4]) = pk;
    }
    __syncthreads();
    #pragma unroll
    for (int i = 0; i < 6; ++i) {
        int t = i * 256 + tid;            // 0..1535: 96 x * 16 cq
        int x = t % 96, cq = t / 96;
        uint32_t w0, w1, w2, w3;
        w0 = (uint32_t)ldsX[(cq * 8 + 0) * 100 + x] | ((uint32_t)ldsX[(cq * 8 + 1) * 100 + x] << 16);
        w1 = (uint32_t)ldsX[(cq * 8 + 2) * 100 + x] | ((uint32_t)ldsX[(cq * 8 + 3) * 100 + x] << 16);
        w2 = (uint32_t)ldsX[(cq * 8 + 4) * 100 + x] | ((uint32_t)ldsX[(cq * 8 + 5) * 100 + x] << 16);
        w3 = (uint32_t)ldsX[(cq * 8 + 6) * 100 + x] | ((uint32_t)ldsX[(cq * 8 + 7) * 100 + x] << 16);
        size_t o = (((size_t)b * HP + (y + 1)) * HP + (x + 1)) * CP + ch * 128 + cq * 8;
        *(uint4*)(cenT + o) = make_uint4(w0, w1, w2, w3);
    }
}

// ---------------------------------------------------------------------------
// Pre-kernel 2: W3 [9][256 n][256 k] fp32 -> W3bf [g][t 8][ks 16][m 32][kh 2][8]
// A-frag (32x32x16: lane m holds k = kh*8 + j) for (g,t,ks) = 1 KiB contiguous.
// ---------------------------------------------------------------------------
__global__ void cvt_w3(const float* __restrict__ W3, uint16_t* __restrict__ W3bf) {
    int e = (blockIdx.x * 256 + threadIdx.x) * 4;   // 0..589823
    int g = e >> 16, n = (e >> 8) & 255, k = e & 255;
    float4 v = *(const float4*)(W3 + e);
    uint2 pk;
    pk.x = (uint32_t)f2bf(v.x) | ((uint32_t)f2bf(v.y) << 16);
    pk.y = (uint32_t)f2bf(v.z) | ((uint32_t)f2bf(v.w) << 16);
    size_t o = (size_t)(((g * 8 + (n >> 5)) * 16 + (k >> 4)) * 512)
             + (n & 31) * 16 + ((k >> 3) & 1) * 8 + (k & 7);
    *(uint2*)(W3bf + o) = pk;
}

// ---------------------------------------------------------------------------
// Main kernel: grid (3 xt, 48 yt, 4 b) = 576 blocks, 512 thr (8 waves).
// Block tile: 64 positions (2 rows x 32 x) x 256 ch; wave w = ch-tile w.
// mfma_f32_32x32x16_bf16, D[ch][pos]; A = W3 frag (global/L2, 1-deep prefetch);
// B = shifted-cen frag (LDS, 1-deep prefetch).
// Norm: 16 in-lane FMA + shfl_xor(32) + ping-pong ldsP -> ONE barrier per g.
// LDS 40 KB, target regs ~110 -> 2 blocks/CU resident.
// ---------------------------------------------------------------------------
__global__ __launch_bounds__(512, 4)
void ecm_main(const float* __restrict__ cen, const uint16_t* __restrict__ cenT,
              const uint16_t* __restrict__ W3bf, float* __restrict__ out) {
    const int tid = threadIdx.x;
    const int wv = tid >> 6, lane = tid & 63, col = lane & 31, kh = lane >> 5;
    const int x0 = blockIdx.x * XT, y0 = blockIdx.y * YT, b = blockIdx.z;

    __shared__ __align__(16) uint16_t ldsA[YT * XE * CP];   // 35,904 B
    __shared__ __align__(16) float ldsP[2][64][8];          // ping-pong norm partials (4 KB)

    // g processed in dy-groups; dgOrd[idx] = reference g index, dx = idx%3 - 1.
    const int dgOrd[9] = {0, 1, 2, 7, 8, 3, 6, 5, 4};

    const uint16_t* wbase = W3bf + (size_t)wv * 16 * 512 + col * 16 + kh * 8;
    f32x16 fin0 = {}, fin1 = {};

    #pragma unroll 1
    for (int idx = 0; idx < 9; ++idx) {
        const int g = dgOrd[idx], dg = idx / 3, dx = idx % 3 - 1;

        if (idx % 3 == 0) {
            // All waves passed the previous g's barrier => their ldsA reads are
            // done (reads precede each wave's ldsP write, which precedes that
            // barrier). Safe to restage without an extra leading barrier.
            for (int r = 0; r < YT; ++r) {
                const uint4* gs = (const uint4*)(cenT + (((size_t)b * HP + (y0 + dg + r)) * HP + x0) * CP);
                uint4* ls = (uint4*)(ldsA + r * XE * CP);
                for (int c = tid; c < XE * CP / 8; c += 512) ls[c] = gs[c];
            }
            __syncthreads();
        }

        const uint16_t* wg = wbase + (size_t)g * 65536;
        const int a0 = (col + dx + 1) * CP + kh * 8;
        const int a1 = a0 + XE * CP;

        f32x16 acc0 = {}, acc1 = {};
        bf16x8 wf = *(const bf16x8*)(wg);
        bf16x8 b0 = *(const bf16x8*)(ldsA + a0);
        bf16x8 b1 = *(const bf16x8*)(ldsA + a1);
        #pragma unroll
        for (int ks = 0; ks < 15; ++ks) {
            bf16x8 wn  = *(const bf16x8*)(wg + (ks + 1) * 512);
            bf16x8 bn0 = *(const bf16x8*)(ldsA + a0 + (ks + 1) * 16);
            bf16x8 bn1 = *(const bf16x8*)(ldsA + a1 + (ks + 1) * 16);
            acc0 = __builtin_amdgcn_mfma_f32_32x32x16_bf16(wf, b0, acc0, 0, 0, 0);
            acc1 = __builtin_amdgcn_mfma_f32_32x32x16_bf16(wf, b1, acc1, 0, 0, 0);
            wf = wn; b0 = bn0; b1 = bn1;
        }
        acc0 = __builtin_amdgcn_mfma_f32_32x32x16_bf16(wf, b0, acc0, 0, 0, 0);
        acc1 = __builtin_amdgcn_mfma_f32_32x32x16_bf16(wf, b1, acc1, 0, 0, 0);

        // Per-position ||Y||^2 partial over this wave's 32 ch.
        float s0 = 0.f, s1 = 0.f;
        #pragma unroll
        for (int r = 0; r < 16; ++r) { s0 += acc0[r] * acc0[r]; s1 += acc1[r] * acc1[r]; }
        s0 += __shfl_xor(s0, 32, 64);
        s1 += __shfl_xor(s1, 32, 64);
        if (kh == 0) { ldsP[idx & 1][col][wv] = s0; ldsP[idx & 1][32 + col][wv] = s1; }
        __syncthreads();   // the ONLY barrier per g (ping-pong covers WAR)

        f32x4 pa = *(const f32x4*)&ldsP[idx & 1][col][0];
        f32x4 pb = *(const f32x4*)&ldsP[idx & 1][col][4];
        f32x4 qa = *(const f32x4*)&ldsP[idx & 1][32 + col][0];
        f32x4 qb = *(const f32x4*)&ldsP[idx & 1][32 + col][4];
        float n0 = pa[0] + pa[1] + pa[2] + pa[3] + pb[0] + pb[1] + pb[2] + pb[3];
        float n1 = qa[0] + qa[1] + qa[2] + qa[3] + qb[0] + qb[1] + qb[2] + qb[3];
        const float sgn = (g == 8) ? 1.f : -1.f;
        float sc0 = sgn / fmaxf(sqrtf(n0), 1e-12f);
        float sc1 = sgn / fmaxf(sqrtf(n1), 1e-12f);
        #pragma unroll
        for (int r = 0; r < 16; ++r) { fin0[r] += acc0[r] * sc0; fin1[r] += acc1[r] * sc1; }
    }

    // Epilogue: out = fin + cen. D row->ch: (reg&3) + 8*(reg>>2) + 4*kh (+32*wv).
    #pragma unroll
    for (int r = 0; r < 16; ++r) {
        int ch = wv * 32 + (r & 3) + 8 * (r >> 2) + 4 * kh;
        size_t o0 = (((size_t)b * CC + ch) * HH + y0) * WW + (x0 + col);
        size_t o1 = o0 + WW;
        out[o0] = fin0[r] + cen[o0];
        out[o1] = fin1[r] + cen[o1];
    }
}

extern "C" void kernel_launch(void* const* d_in, const int* in_sizes, int n_in,
                              void* d_out, int out_size, void* d_ws, size_t ws_size,
                              hipStream_t stream) {
    const float* cen = (const float*)d_in[0];
    // d_in[1] = W1, d_in[2] = W2: dead code (softmax over size-1 axis == 1.0)
    const float* W3 = (const float*)d_in[3];
    float* out = (float*)d_out;

    uint16_t* cenT = (uint16_t*)d_ws;                         // [4][98][98][264] bf16
    const size_t cenT_elems = (size_t)BB * HP * HP * CP;
    uint16_t* W3bf = cenT + cenT_elems;                       // [9][8][16][512] bf16

    hipMemsetAsync(d_ws, 0, cenT_elems * sizeof(uint16_t), stream);   // zero halos
    transpose_cen<<<dim3(HH, BB, 2), 256, 0, stream>>>(cen, cenT);
    cvt_w3<<<576, 256, 0, stream>>>(W3, W3bf);
    ecm_main<<<dim3(3, 48, 4), 512, 0, stream>>>(cen, cenT, W3bf, out);
}